// Round 1
// baseline (420.204 us; speedup 1.0000x reference)
//
#include <hip/hip_runtime.h>

typedef __attribute__((ext_vector_type(8))) short bf16x8;
typedef __attribute__((ext_vector_type(16))) float f32x16;

#define HH 8
#define DD 32
#define NB 512
#define BS 128
#define LKB 40    // K row stride (elems): 32 + 8 pad
#define LVT 136   // Vt row stride (elems): 128 + 8 pad

// packed fp32x2 -> bf16x2, RNE (single instruction on gfx950)
__device__ __forceinline__ unsigned int cvtpk(float a, float b) {
    unsigned int r;
    asm("v_cvt_pk_bf16_f32 %0, %1, %2" : "=v"(r) : "v"(a), "v"(b));
    return r;
}

__global__ __launch_bounds__(256, 4) void battn_kernel(
    const float* __restrict__ Qg, const float* __restrict__ Kg,
    const float* __restrict__ Vg, const int* __restrict__ SB,
    float* __restrict__ Og)
{
    __shared__ unsigned short Kb[BS * LKB];   // K bf16 [key][d]
    __shared__ unsigned short Vt[DD * LVT];   // V bf16 [d][sigma(key)]  (key bits 2<->3 swapped)

    const int bid = blockIdx.x;
    const int h = bid & 7;
    const int n = (bid >> 3) & (NB - 1);
    const int b = bid >> 12;
    const int tid = threadIdx.x;
    const int base = ((b * 65536 + n * BS) * HH + h) * DD;

    // ---------------- staging: K, V global fp32 -> LDS bf16 ----------------
    {
        const int tok = tid >> 1, half = tid & 1;
        const float4* kv = (const float4*)(Kg + base + tok * (HH * DD) + half * 16);
        float4 c0 = kv[0], c1 = kv[1], c2 = kv[2], c3 = kv[3];
        uint4* kd = (uint4*)(Kb + tok * LKB + half * 16);
        kd[0] = make_uint4(cvtpk(c0.x, c0.y), cvtpk(c0.z, c0.w),
                           cvtpk(c1.x, c1.y), cvtpk(c1.z, c1.w));
        kd[1] = make_uint4(cvtpk(c2.x, c2.y), cvtpk(c2.z, c2.w),
                           cvtpk(c3.x, c3.y), cvtpk(c3.z, c3.w));

        // V: thread owns 4 keys x 4 d; in-register 4x4 transpose, vector LDS writes.
        const int kg = tid >> 3, dq = tid & 7;
        const float* vb = Vg + base + (kg * 4) * (HH * DD) + dq * 4;
        float4 v0 = *(const float4*)(vb);
        float4 v1 = *(const float4*)(vb + HH * DD);
        float4 v2 = *(const float4*)(vb + 2 * HH * DD);
        float4 v3 = *(const float4*)(vb + 3 * HH * DD);
        // sigma: swap key bits 2,3  ==  swap kg bits 0,1 (keys kg*4+i -> kgp*4+i)
        const int kgp = (kg & ~3) | ((kg & 1) << 1) | ((kg >> 1) & 1);
        *(uint2*)(Vt + (dq * 4 + 0) * LVT + kgp * 4) = make_uint2(cvtpk(v0.x, v1.x), cvtpk(v2.x, v3.x));
        *(uint2*)(Vt + (dq * 4 + 1) * LVT + kgp * 4) = make_uint2(cvtpk(v0.y, v1.y), cvtpk(v2.y, v3.y));
        *(uint2*)(Vt + (dq * 4 + 2) * LVT + kgp * 4) = make_uint2(cvtpk(v0.z, v1.z), cvtpk(v2.z, v3.z));
        *(uint2*)(Vt + (dq * 4 + 3) * LVT + kgp * 4) = make_uint2(cvtpk(v0.w, v1.w), cvtpk(v2.w, v3.w));
    }

    const int lane = tid & 63;
    const int w = tid >> 6;        // wave id: owns queries [w*32, w*32+32)
    const int l31 = lane & 31;
    const int hi = lane >> 5;
    const int q0row = w * 32;

    // Q fragments direct from global (wave-private; each 128B row line fully used by its hi0/hi1 pair)
    // fold softmax scale AND log2(e) into Q so scores are in exp2 domain
    bf16x8 qf0, qf1;
    {
        const float cs = 0.17677669529663687f * 1.4426950408889634f;
        const float* qr = Qg + base + (q0row + l31) * (HH * DD) + hi * 8;
        float4 a0 = *(const float4*)(qr);
        float4 a1 = *(const float4*)(qr + 4);
        float4 a2 = *(const float4*)(qr + 16);
        float4 a3 = *(const float4*)(qr + 20);
        qf0 = __builtin_bit_cast(bf16x8, make_uint4(
              cvtpk(a0.x * cs, a0.y * cs), cvtpk(a0.z * cs, a0.w * cs),
              cvtpk(a1.x * cs, a1.y * cs), cvtpk(a1.z * cs, a1.w * cs)));
        qf1 = __builtin_bit_cast(bf16x8, make_uint4(
              cvtpk(a2.x * cs, a2.y * cs), cvtpk(a2.z * cs, a2.w * cs),
              cvtpk(a3.x * cs, a3.y * cs), cvtpk(a3.z * cs, a3.w * cs)));
    }
    __syncthreads();

    const int sb = (b * NB + n) * 2;
    const int st = SB[sb], en = SB[sb + 1];
    const int kbase = n * BS;

    const f32x16 z = {0.f,0.f,0.f,0.f, 0.f,0.f,0.f,0.f, 0.f,0.f,0.f,0.f, 0.f,0.f,0.f,0.f};

    // S^T: A = K (M=key), B = Q (N=query). 32x32x16, two K-steps cover D=32.
    // C layout: col(query)=l31, row(key in tile)=(r&3)+8*(r>>2)+4*hi
    f32x16 acc[4];
    #pragma unroll
    for (int kt = 0; kt < 4; ++kt) {
        const unsigned short* kp = Kb + (kt * 32 + l31) * LKB + hi * 8;
        bf16x8 kf0 = *(const bf16x8*)(kp);
        bf16x8 kf1 = *(const bf16x8*)(kp + 16);
        acc[kt] = __builtin_amdgcn_mfma_f32_32x32x16_bf16(kf0, qf0, z, 0, 0, 0);
        acc[kt] = __builtin_amdgcn_mfma_f32_32x32x16_bf16(kf1, qf1, acc[kt], 0, 0, 0);
    }

    // mask (skipped entirely for full buckets - wave-uniform branch) + row max
    const bool full = (st <= kbase) && (en >= kbase + BS);
    float mx;
    {
        float m0 = -1.0e30f, m1 = -1.0e30f, m2 = -1.0e30f, m3 = -1.0e30f;
        if (full) {
            #pragma unroll
            for (int r = 0; r < 16; ++r) {
                m0 = fmaxf(m0, acc[0][r]); m1 = fmaxf(m1, acc[1][r]);
                m2 = fmaxf(m2, acc[2][r]); m3 = fmaxf(m3, acc[3][r]);
            }
        } else {
            #pragma unroll
            for (int kt = 0; kt < 4; ++kt) {
                #pragma unroll
                for (int r = 0; r < 16; ++r) {
                    const int ap = kbase + kt * 32 + ((r & 3) + 8 * (r >> 2) + 4 * hi);
                    float s = ((ap >= st) && (ap < en)) ? acc[kt][r] : -1.0e30f;
                    acc[kt][r] = s;
                    m0 = fmaxf(m0, s);
                }
            }
        }
        mx = fmaxf(fmaxf(m0, m1), fmaxf(m2, m3));
    }
    mx = fmaxf(mx, __shfl_xor(mx, 32));   // keys split across hi halves

    // Fused softmax + PV. Key permutation sigma (V rows pre-swizzled) makes the
    // PV A-operand exactly the lane's own P values packed in register order:
    // step s consumes acc[s>>1] regs [8*(s&1) .. +8) -> one 32x32x16 MFMA.
    f32x16 o = z;
    float ssum = 0.f;
    #pragma unroll
    for (int s = 0; s < 8; ++s) {
        const int kt = s >> 1;
        const int rb = 8 * (s & 1);
        float p0 = exp2f(acc[kt][rb + 0] - mx);
        float p1 = exp2f(acc[kt][rb + 1] - mx);
        float p2 = exp2f(acc[kt][rb + 2] - mx);
        float p3 = exp2f(acc[kt][rb + 3] - mx);
        float p4 = exp2f(acc[kt][rb + 4] - mx);
        float p5 = exp2f(acc[kt][rb + 5] - mx);
        float p6 = exp2f(acc[kt][rb + 6] - mx);
        float p7 = exp2f(acc[kt][rb + 7] - mx);
        ssum += ((p0 + p1) + (p2 + p3)) + ((p4 + p5) + (p6 + p7));
        bf16x8 pa = __builtin_bit_cast(bf16x8, make_uint4(
            cvtpk(p0, p1), cvtpk(p2, p3), cvtpk(p4, p5), cvtpk(p6, p7)));
        bf16x8 vf = *(const bf16x8*)(Vt + l31 * LVT + s * 16 + hi * 8);
        o = __builtin_amdgcn_mfma_f32_32x32x16_bf16(pa, vf, o, 0, 0, 0);
    }
    ssum += __shfl_xor(ssum, 32);
    const float inv = 1.0f / ssum;        // lane holds denom for query q0row+l31

    // epilogue: normalize (inv fetched cross-lane), gate invalid queries, store fp32
    #pragma unroll
    for (int r = 0; r < 16; ++r) {
        const int row = (r & 3) + 8 * (r >> 2) + 4 * hi;
        const int q = q0row + row;
        float iv = __shfl(inv, row);
        if (!full) {
            const int ap = kbase + q;
            iv = ((ap >= st) && (ap < en)) ? iv : 0.f;
        }
        Og[base + q * (HH * DD) + l31] = o[r] * iv;
    }
}

extern "C" void kernel_launch(void* const* d_in, const int* in_sizes, int n_in,
                              void* d_out, int out_size, void* d_ws, size_t ws_size,
                              hipStream_t stream) {
    const float* Q = (const float*)d_in[0];
    const float* K = (const float*)d_in[1];
    const float* V = (const float*)d_in[2];
    const int* SB  = (const int*)d_in[3];
    float* O = (float*)d_out;
    battn_kernel<<<dim3(8192), dim3(256), 0, stream>>>(Q, K, V, SB, O);
}

// Round 2
// 419.074 us; speedup vs baseline: 1.0027x; 1.0027x over previous
//
#include <hip/hip_runtime.h>

typedef __attribute__((ext_vector_type(8))) short bf16x8;
typedef __attribute__((ext_vector_type(16))) float f32x16;

#define HH 8
#define DD 32
#define NB 512
#define BS 128
#define LKB 40    // K row stride (elems): 32 + 8 pad
#define LVT 136   // Vt row stride (elems): 128 + 8 pad

// packed fp32x2 -> bf16x2, RNE (single instruction on gfx950)
__device__ __forceinline__ unsigned int cvtpk(float a, float b) {
    unsigned int r;
    asm("v_cvt_pk_bf16_f32 %0, %1, %2" : "=v"(r) : "v"(a), "v"(b));
    return r;
}

__global__ __launch_bounds__(256, 4) void battn_kernel(
    const float* __restrict__ Qg, const float* __restrict__ Kg,
    const float* __restrict__ Vg, const int* __restrict__ SB,
    float* __restrict__ Og)
{
    __shared__ unsigned short Kb[BS * LKB];   // K bf16 [key][d]
    __shared__ unsigned short Vt[DD * LVT];   // V bf16 [d][sigma(key)]  (key bits 2<->3 swapped)

    const int bid = blockIdx.x;
    const int h = bid & 7;
    const int n = (bid >> 3) & (NB - 1);
    const int b = bid >> 12;
    const int tid = threadIdx.x;
    const int base = ((b * 65536 + n * BS) * HH + h) * DD;

    // ---------------- staging: K, V global fp32 -> LDS bf16 ----------------
    {
        const int tok = tid >> 1, half = tid & 1;
        const float4* kv = (const float4*)(Kg + base + tok * (HH * DD) + half * 16);
        float4 c0 = kv[0], c1 = kv[1], c2 = kv[2], c3 = kv[3];
        uint4* kd = (uint4*)(Kb + tok * LKB + half * 16);
        kd[0] = make_uint4(cvtpk(c0.x, c0.y), cvtpk(c0.z, c0.w),
                           cvtpk(c1.x, c1.y), cvtpk(c1.z, c1.w));
        kd[1] = make_uint4(cvtpk(c2.x, c2.y), cvtpk(c2.z, c2.w),
                           cvtpk(c3.x, c3.y), cvtpk(c3.z, c3.w));

        // V: thread owns 4 keys x 4 d; in-register 4x4 transpose, vector LDS writes.
        const int kg = tid >> 3, dq = tid & 7;
        const float* vb = Vg + base + (kg * 4) * (HH * DD) + dq * 4;
        float4 v0 = *(const float4*)(vb);
        float4 v1 = *(const float4*)(vb + HH * DD);
        float4 v2 = *(const float4*)(vb + 2 * HH * DD);
        float4 v3 = *(const float4*)(vb + 3 * HH * DD);
        // sigma: swap key bits 2,3  ==  swap kg bits 0,1 (keys kg*4+i -> kgp*4+i)
        const int kgp = (kg & ~3) | ((kg & 1) << 1) | ((kg >> 1) & 1);
        *(uint2*)(Vt + (dq * 4 + 0) * LVT + kgp * 4) = make_uint2(cvtpk(v0.x, v1.x), cvtpk(v2.x, v3.x));
        *(uint2*)(Vt + (dq * 4 + 1) * LVT + kgp * 4) = make_uint2(cvtpk(v0.y, v1.y), cvtpk(v2.y, v3.y));
        *(uint2*)(Vt + (dq * 4 + 2) * LVT + kgp * 4) = make_uint2(cvtpk(v0.z, v1.z), cvtpk(v2.z, v3.z));
        *(uint2*)(Vt + (dq * 4 + 3) * LVT + kgp * 4) = make_uint2(cvtpk(v0.w, v1.w), cvtpk(v2.w, v3.w));
    }

    const int lane = tid & 63;
    const int w = tid >> 6;        // wave id: owns queries [w*32, w*32+32)
    const int l31 = lane & 31;
    const int hi = lane >> 5;
    const int q0row = w * 32;

    // Q fragments direct from global (wave-private; each 128B row fully used by its hi0/hi1 lane pair)
    // fold softmax scale AND log2(e) into Q so scores are in exp2 domain
    bf16x8 qf0, qf1;
    {
        const float cs = 0.17677669529663687f * 1.4426950408889634f;
        const float* qr = Qg + base + (q0row + l31) * (HH * DD) + hi * 8;
        float4 a0 = *(const float4*)(qr);
        float4 a1 = *(const float4*)(qr + 4);
        float4 a2 = *(const float4*)(qr + 16);
        float4 a3 = *(const float4*)(qr + 20);
        qf0 = __builtin_bit_cast(bf16x8, make_uint4(
              cvtpk(a0.x * cs, a0.y * cs), cvtpk(a0.z * cs, a0.w * cs),
              cvtpk(a1.x * cs, a1.y * cs), cvtpk(a1.z * cs, a1.w * cs)));
        qf1 = __builtin_bit_cast(bf16x8, make_uint4(
              cvtpk(a2.x * cs, a2.y * cs), cvtpk(a2.z * cs, a2.w * cs),
              cvtpk(a3.x * cs, a3.y * cs), cvtpk(a3.z * cs, a3.w * cs)));
    }

    const int sb = (b * NB + n) * 2;
    const int st = SB[sb], en = SB[sb + 1];
    const int kbase = n * BS;
    const bool full = (st <= kbase) && (en >= kbase + BS);

    __syncthreads();

    const f32x16 z = {0.f,0.f,0.f,0.f, 0.f,0.f,0.f,0.f, 0.f,0.f,0.f,0.f, 0.f,0.f,0.f,0.f};

    // Flash-style online softmax over four 32-key tiles: only ONE f32x16 score
    // tile live at a time (keeps total live regs < 128 -> no spill at 4 waves/SIMD).
    // S^T: A = K (M=key), B = Q (N=query). C layout: col(query)=l31,
    // row(key in tile)=(r&3)+8*(r>>2)+4*hi.
    // Key permutation sigma (V pre-swizzled) makes the PV A-operand exactly the
    // lane's own P values in register order: sub-step j consumes s regs [8j..8j+8).
    f32x16 o = z;
    float m = -30.0f;   // running max (floored: masked tiles give p=exp2(-huge)=0)
    float l = 0.f;

    #pragma unroll
    for (int kt = 0; kt < 4; ++kt) {
        const unsigned short* kp = Kb + (kt * 32 + l31) * LKB + hi * 8;
        bf16x8 kf0 = *(const bf16x8*)(kp);
        bf16x8 kf1 = *(const bf16x8*)(kp + 16);
        f32x16 s = __builtin_amdgcn_mfma_f32_32x32x16_bf16(kf0, qf0, z, 0, 0, 0);
        s = __builtin_amdgcn_mfma_f32_32x32x16_bf16(kf1, qf1, s, 0, 0, 0);

        if (!full) {   // block-uniform branch
            #pragma unroll
            for (int r = 0; r < 16; ++r) {
                const int ap = kbase + kt * 32 + ((r & 3) + 8 * (r >> 2) + 4 * hi);
                s[r] = ((ap >= st) && (ap < en)) ? s[r] : -1.0e30f;
            }
        }

        float tmax = s[0];
        #pragma unroll
        for (int r = 1; r < 16; ++r) tmax = fmaxf(tmax, s[r]);
        tmax = fmaxf(tmax, __shfl_xor(tmax, 32));   // unify across hi halves

        if (kt == 0) {
            m = fmaxf(tmax, -30.0f);
        } else if (__any(tmax > m + 8.0f)) {   // deferred rescale (T13, THR=8)
            const float nm = fmaxf(m, tmax);
            const float sc = exp2f(m - nm);
            #pragma unroll
            for (int r = 0; r < 16; ++r) o[r] *= sc;
            l *= sc;
            m = nm;
        }

        #pragma unroll
        for (int j = 0; j < 2; ++j) {
            const int rb = 8 * j;
            float p0 = exp2f(s[rb + 0] - m);
            float p1 = exp2f(s[rb + 1] - m);
            float p2 = exp2f(s[rb + 2] - m);
            float p3 = exp2f(s[rb + 3] - m);
            float p4 = exp2f(s[rb + 4] - m);
            float p5 = exp2f(s[rb + 5] - m);
            float p6 = exp2f(s[rb + 6] - m);
            float p7 = exp2f(s[rb + 7] - m);
            l += ((p0 + p1) + (p2 + p3)) + ((p4 + p5) + (p6 + p7));
            bf16x8 pa = __builtin_bit_cast(bf16x8, make_uint4(
                cvtpk(p0, p1), cvtpk(p2, p3), cvtpk(p4, p5), cvtpk(p6, p7)));
            bf16x8 vf = *(const bf16x8*)(Vt + l31 * LVT + (kt * 2 + j) * 16 + hi * 8);
            o = __builtin_amdgcn_mfma_f32_32x32x16_bf16(pa, vf, o, 0, 0, 0);
        }
    }

    l += __shfl_xor(l, 32);
    const float inv = 1.0f / l;          // lane holds denom for query q0row+l31

    // epilogue: normalize (inv fetched cross-lane), gate invalid queries, store fp32
    #pragma unroll
    for (int r = 0; r < 16; ++r) {
        const int row = (r & 3) + 8 * (r >> 2) + 4 * hi;
        const int q = q0row + row;
        float iv = __shfl(inv, row);
        if (!full) {
            const int ap = kbase + q;
            iv = ((ap >= st) && (ap < en)) ? iv : 0.f;
        }
        Og[base + q * (HH * DD) + l31] = o[r] * iv;
    }
}

extern "C" void kernel_launch(void* const* d_in, const int* in_sizes, int n_in,
                              void* d_out, int out_size, void* d_ws, size_t ws_size,
                              hipStream_t stream) {
    const float* Q = (const float*)d_in[0];
    const float* K = (const float*)d_in[1];
    const float* V = (const float*)d_in[2];
    const int* SB  = (const int*)d_in[3];
    float* O = (float*)d_out;
    battn_kernel<<<dim3(8192), dim3(256), 0, stream>>>(Q, K, V, SB, O);
}